// Round 4
// baseline (794.300 us; speedup 1.0000x reference)
//
#include <hip/hip_runtime.h>
#include <hip/hip_cooperative_groups.h>
#include <hip/hip_bf16.h>
#include <stdint.h>
#include <math.h>

namespace cg = cooperative_groups;

#define T_TOKENS 16384
#define DIM      512
#define NEXP     8
#define HID      2048

typedef __attribute__((ext_vector_type(8))) __bf16 bf16x8;
typedef __attribute__((ext_vector_type(16))) float f32x16;

__device__ __forceinline__ f32x16 mfma32(bf16x8 a, bf16x8 b, f32x16 c) {
  return __builtin_amdgcn_mfma_f32_32x32x16_bf16(a, b, c, 0, 0, 0);
}

// async global->LDS DMA, 16B/lane; LDS dest = wave-uniform base + lane*16
__device__ __forceinline__ void glds16(const __bf16* g, __bf16* l) {
  __builtin_amdgcn_global_load_lds((const __attribute__((address_space(1))) void*)g,
                                   (__attribute__((address_space(3))) void*)l, 16, 0, 0);
}

#define WAITVM(n) asm volatile("s_waitcnt vmcnt(" #n ")" ::: "memory")
#define WAITLGKM0 asm volatile("s_waitcnt lgkmcnt(0)" ::: "memory")
#define SBAR      asm volatile("s_barrier" ::: "memory")
#define SCHEDB    __builtin_amdgcn_sched_barrier(0)
#define ADV3(v)   v = ((v) == 2) ? 0 : ((v) + 1)

// ---- JAX threefry2x32, key = (0, 42) ----
__device__ __forceinline__ void threefry2x32(uint32_t k0, uint32_t k1,
                                             uint32_t x0, uint32_t x1,
                                             uint32_t* o0, uint32_t* o1) {
  uint32_t ks0 = k0, ks1 = k1, ks2 = k0 ^ k1 ^ 0x1BD11BDAu;
#define TF_ROT(v, d) (((v) << (d)) | ((v) >> (32 - (d))))
#define TF_ROUND(r) { x0 += x1; x1 = TF_ROT(x1, r); x1 ^= x0; }
  x0 += ks0; x1 += ks1;
  TF_ROUND(13) TF_ROUND(15) TF_ROUND(26) TF_ROUND(6)
  x0 += ks1; x1 += ks2 + 1u;
  TF_ROUND(17) TF_ROUND(29) TF_ROUND(16) TF_ROUND(24)
  x0 += ks2; x1 += ks0 + 2u;
  TF_ROUND(13) TF_ROUND(15) TF_ROUND(26) TF_ROUND(6)
  x0 += ks0; x1 += ks1 + 3u;
  TF_ROUND(17) TF_ROUND(29) TF_ROUND(16) TF_ROUND(24)
  x0 += ks1; x1 += ks2 + 4u;
  TF_ROUND(13) TF_ROUND(15) TF_ROUND(26) TF_ROUND(6)
  x0 += ks2; x1 += ks0 + 5u;
#undef TF_ROUND
#undef TF_ROT
  *o0 = x0; *o1 = x1;
}

// ---- XLA ErfInv32 (Giles polynomial) ----
__device__ __forceinline__ float erfinv_xla(float x) {
  float w = -log1pf(__fmul_rn(-x, x));
  float p;
  if (w < 5.0f) {
    w = __fadd_rn(w, -2.5f);
    p = 2.81022636e-08f;
    p = __fadd_rn(3.43273939e-07f, __fmul_rn(p, w));
    p = __fadd_rn(-3.5233877e-06f, __fmul_rn(p, w));
    p = __fadd_rn(-4.39150654e-06f, __fmul_rn(p, w));
    p = __fadd_rn(0.00021858087f, __fmul_rn(p, w));
    p = __fadd_rn(-0.00125372503f, __fmul_rn(p, w));
    p = __fadd_rn(-0.00417768164f, __fmul_rn(p, w));
    p = __fadd_rn(0.246640727f, __fmul_rn(p, w));
    p = __fadd_rn(1.50140941f, __fmul_rn(p, w));
  } else {
    w = __fadd_rn(sqrtf(w), -3.0f);
    p = -0.000200214257f;
    p = __fadd_rn(0.000100950558f, __fmul_rn(p, w));
    p = __fadd_rn(0.00134934322f, __fmul_rn(p, w));
    p = __fadd_rn(-0.00367342844f, __fmul_rn(p, w));
    p = __fadd_rn(0.00573950773f, __fmul_rn(p, w));
    p = __fadd_rn(-0.0076224613f, __fmul_rn(p, w));
    p = __fadd_rn(0.00943887047f, __fmul_rn(p, w));
    p = __fadd_rn(1.00167406f, __fmul_rn(p, w));
    p = __fadd_rn(2.83297682f, __fmul_rn(p, w));
  }
  return __fmul_rn(p, x);
}

__device__ __forceinline__ float jax_normal_at(uint32_t i) {
  uint32_t o0, o1;
  threefry2x32(0u, 42u, 0u, i, &o0, &o1);
  uint32_t bits = o0 ^ o1;
  float f = __fadd_rn(__uint_as_float((bits >> 9) | 0x3f800000u), -1.0f);
  const float lo = -0.99999994f;
  float u = fmaxf(lo, __fadd_rn(__fmul_rn(f, 2.0f), lo));
  return __fmul_rn(1.4142135623730951f, erfinv_xla(u));
}

// =======================================================================
// ONE cooperative kernel: zero+pack+router -> sync -> count/rank -> sync
// -> list-write -> sync -> expert FFN (R3-proven DMA-ring structure).
// 256 blocks x 512 threads, 148 KB LDS -> exactly 1 block/CU.
// =======================================================================
__global__ __launch_bounds__(512) void fused_moe(
    const float* __restrict__ x, const float* __restrict__ Wr, const float* __restrict__ br,
    const float* __restrict__ Wn, const float* __restrict__ bn,
    const float* __restrict__ W1, const float* __restrict__ b1,
    const float* __restrict__ W2, const float* __restrict__ b2,
    __bf16* __restrict__ W1p, __bf16* __restrict__ W2p,
    int* __restrict__ fill,
    int* __restrict__ ltok, float* __restrict__ lgate,
    float* __restrict__ out) {
  __shared__ __align__(16) char SMEM[147456];   // Xs 64K | Hs 32K | Rings 48K (aliased by pack/router)
  __shared__ int   toks[64];
  __shared__ float gates[64];
  __shared__ int   lhist[8], lbase[8], loffs[8];

  const int tid  = threadIdx.x;
  const int lane = tid & 63;
  const int w    = tid >> 6;
  cg::grid_group grid = cg::this_grid();

  // ---------------- Phase A1: zero out + control ----------------
  {
    float4 z4 = {0.f, 0.f, 0.f, 0.f};
    float4* o4 = (float4*)out;
    int gtid = blockIdx.x * 512 + tid;
#pragma unroll
    for (int i = 0; i < 16; ++i) o4[gtid + i * 131072] = z4;   // 8.4M floats
    if (blockIdx.x == 0 && tid < 8) fill[tid] = 0;
  }

  // ---------------- Phase A2: transpose-pack W1,W2 -> bf16 frags ----------------
  // dst[e][nt][ko][lc][j] = src[e][ko*8+j][nt*32+lc]
  {
    float (*Ls)[68] = (float(*)[68])SMEM;
#pragma unroll 1
    for (int i = 0; i < 16; ++i) {
      int v = blockIdx.x * 16 + i;                 // 0..4095 virtual tiles
      const float* src; __bf16* dst; int R, C, e4, rt, ct;
      if (v < 2048) {                              // W1: 8e x (8 rt x 32 ct)
        e4 = v >> 8; int rem = v & 255; rt = rem >> 5; ct = rem & 31;
        src = W1; dst = W1p; R = 512; C = 2048;
      } else {                                     // W2: 8e x (32 rt x 8 ct)
        int v2 = v - 2048;
        e4 = v2 >> 8; int rem = v2 & 255; rt = rem >> 3; ct = rem & 7;
        src = W2; dst = W2p; R = 2048; C = 512;
      }
      const float* s = src + (size_t)e4 * R * C + (size_t)(rt * 64) * C + ct * 64;
#pragma unroll
      for (int it = 0; it < 2; ++it) {
        int i4 = tid + it * 512;                   // 1024 float4 slots
        int row = i4 >> 4, col = (i4 & 15) * 4;
        *(float4*)&Ls[row][col] = *(const float4*)(s + (size_t)row * C + col);
      }
      __syncthreads();
      {
        int lc = tid & 31, kol = (tid >> 5) & 7, ntl = tid >> 8;
        int KO = R >> 3;
        bf16x8 vv;
#pragma unroll
        for (int j = 0; j < 8; ++j) vv[j] = (__bf16)Ls[kol * 8 + j][ntl * 32 + lc];
        size_t idx = ((size_t)(e4 * (C >> 5) + ct * 2 + ntl) * KO + rt * 8 + kol) * 256 + lc * 8;
        *(bf16x8*)(dst + idx) = vv;
      }
      __syncthreads();
    }
  }

  // ---------------- Phase A3: router (results stay in registers) ----------------
  int i1_0 = 0, i2_0 = 0, i1_1 = 0, i2_1 = 0;
  float g1_0 = 0.f, g2_0 = 0.f, g1_1 = 0.f, g2_1 = 0.f;
  {
    float* WrS = (float*)SMEM;                     // 4224 floats (+8/32-row pad)
    float* WnS = (float*)(SMEM + 16896);
#pragma unroll
    for (int i = 0; i < 2; ++i) {
      int i4 = tid + i * 512;                      // 0..1023
      int d = i4 >> 1, eh = (i4 & 1) * 4;
      *(float4*)&WrS[d * 8 + (d >> 5) * 8 + eh] = ((const float4*)Wr)[i4];
      *(float4*)&WnS[d * 8 + (d >> 5) * 8 + eh] = ((const float4*)Wn)[i4];
    }
    __syncthreads();

    const int tl = lane & 3, dq = lane >> 2;
#pragma unroll
    for (int p = 0; p < 2; ++p) {
      int t = blockIdx.x * 64 + p * 32 + w * 4 + tl;

      const float* xp = x + (size_t)t * DIM + dq * 32;
      float xv[32];
#pragma unroll
      for (int i = 0; i < 8; ++i) {
        float4 f = *(const float4*)(xp + i * 4);
        xv[i * 4 + 0] = f.x; xv[i * 4 + 1] = f.y; xv[i * 4 + 2] = f.z; xv[i * 4 + 3] = f.w;
      }
      double accR[8], accN[8];
#pragma unroll
      for (int e2 = 0; e2 < 8; ++e2) { accR[e2] = 0.0; accN[e2] = 0.0; }
#pragma unroll
      for (int r = 0; r < 32; ++r) {
        int d = dq * 32 + r;
        const float* wr = &WrS[d * 8 + (d >> 5) * 8];
        const float* wn = &WnS[d * 8 + (d >> 5) * 8];
        double xd = (double)xv[r];
#pragma unroll
        for (int e2 = 0; e2 < 8; ++e2) {
          accR[e2] += xd * (double)wr[e2];
          accN[e2] += xd * (double)wn[e2];
        }
      }
#pragma unroll
      for (int m = 4; m <= 32; m <<= 1) {
#pragma unroll
        for (int e2 = 0; e2 < 8; ++e2) {
          accR[e2] += __shfl_xor(accR[e2], m);
          accN[e2] += __shfl_xor(accN[e2], m);
        }
      }
      const int el = (lane >> 2) & 7;
      double accRm = 0.0, accNm = 0.0;
#pragma unroll
      for (int e2 = 0; e2 < 8; ++e2) {
        double vR = __shfl(accR[e2], tl);
        double vN = __shfl(accN[e2], tl);
        if (e2 == el) { accRm = vR; accNm = vN; }
      }
      double noisy = -1.0e308;
      if (lane < 32) {
        double logit = accRm + (double)br[el];
        double nlin  = accNm + (double)bn[el];
        double noise = (double)jax_normal_at((uint32_t)t * 8u + (uint32_t)el);
        double sp = fmax(nlin, 0.0) + log1p(exp(-fabs(nlin)));
        noisy = logit + noise * sp;
      }
      double v[8];
#pragma unroll
      for (int e2 = 0; e2 < 8; ++e2) v[e2] = __shfl(noisy, tl + 4 * e2);

      if (lane < 4) {
        int i1 = 0; double v1 = v[0];
#pragma unroll
        for (int e2 = 1; e2 < 8; ++e2) if (v[e2] > v1) { v1 = v[e2]; i1 = e2; }
        int i2 = -1; double v2 = -1.0e308;
#pragma unroll
        for (int e2 = 0; e2 < 8; ++e2) if (e2 != i1 && v[e2] > v2) { v2 = v[e2]; i2 = e2; }
        double w2 = exp(v2 - v1);
        double s = 1.0 + w2;
        float g1 = (float)(1.0 / s), g2 = (float)(w2 / s);
        if (p == 0) { i1_0 = i1; i2_0 = i2; g1_0 = g1; g2_0 = g2; }
        else        { i1_1 = i1; i2_1 = i2; g1_1 = g1; g2_1 = g2; }
      }
    }
  }

  __threadfence();
  grid.sync();

  // ---------------- Phase B1: block-aggregated count + rank ----------------
  if (tid < 8) lhist[tid] = 0;
  __syncthreads();
  int r10 = 0, r20 = 0, r11 = 0, r21 = 0;
  if (lane < 4) {
    r10 = atomicAdd(&lhist[i1_0], 1);
    r20 = atomicAdd(&lhist[i2_0], 1);
    r11 = atomicAdd(&lhist[i1_1], 1);
    r21 = atomicAdd(&lhist[i2_1], 1);
  }
  __syncthreads();
  if (tid < 8) lbase[tid] = atomicAdd(&fill[tid], lhist[tid]);   // 8 global atomics/block
  __threadfence();
  grid.sync();

  // ---------------- Phase B2: offsets + list writes ----------------
  if (tid < 8) {
    int o = 0;
#pragma unroll
    for (int j = 0; j < 8; ++j) { int c = (fill[j] + 63) & ~63; if (j < tid) o += c; }
    loffs[tid] = o;
  }
  __syncthreads();
  if (lane < 4) {
    const int tl = lane & 3;
    int t0 = blockIdx.x * 64 + w * 4 + tl;
    int t1 = t0 + 32;
    int d;
    d = loffs[i1_0] + lbase[i1_0] + r10; ltok[d] = t0; lgate[d] = g1_0;
    d = loffs[i2_0] + lbase[i2_0] + r20; ltok[d] = t0; lgate[d] = g2_0;
    d = loffs[i1_1] + lbase[i1_1] + r11; ltok[d] = t1; lgate[d] = g1_1;
    d = loffs[i2_1] + lbase[i2_1] + r21; ltok[d] = t1; lgate[d] = g2_1;
  }
  __threadfence();
  grid.sync();

  // ---------------- Phase C: expert FFN (R3-proven structure) ----------------
  {
    const int e = blockIdx.x & 7;          // XCD-pinned expert
    const int tslot = blockIdx.x >> 3;     // 0..31

    __bf16* Xs = (__bf16*)SMEM;                         // 64 KB
    __bf16* Hs = (__bf16*)(SMEM + 65536);               // 32 KB
    __bf16* ringW = (__bf16*)(SMEM + 98304 + w * 6144); // 3 x 2KB per wave

    const int hi = lane >> 5;
    const int lm = lane & 31;

    int cnt = 0, off = 0;
#pragma unroll
    for (int j = 0; j < NEXP; ++j) {
      int c = fill[j];
      if (j == e) cnt = c;
      if (j < e) off += (c + 63) & ~63;
    }

    const __bf16* W1e = W1p + (size_t)e * (64 * 64 * 256);
    const __bf16* W2e = W2p + (size_t)e * (16 * 256 * 256);

    const float b2r0 = b2[e * DIM + (2 * w + 0) * 32 + lm];
    const float b2r1 = b2[e * DIM + (2 * w + 1) * 32 + lm];

    auto issueStage = [&](int g, int slot) {
      int hc = g >> 5, ss = g & 15;
      __bf16* dst = ringW + slot * 1024;
      if (((g >> 4) & 1) == 0) {
        int nt = hc * 8 + w;
        const __bf16* src = W1e + ((size_t)(nt * 64 + ss * 4)) * 256 + lane * 8;
        glds16(src, dst);
        glds16(src + 512, dst + 512);
      } else {
        int ko2 = hc * 32 + ss * 2;
        glds16(W2e + ((size_t)((2 * w) * 256 + ko2)) * 256 + lane * 8, dst);
        glds16(W2e + ((size_t)((2 * w + 1) * 256 + ko2)) * 256 + lane * 8, dst + 512);
      }
    };

    for (int tile = tslot; tile * 64 < cnt; tile += 32) {
      int start = tile * 64;
      int nrow = min(64, cnt - start);
      int base = off + start;

      issueStage(0, 0);
      issueStage(1, 1);

      SBAR;                                // prev tile's epilogue done with toks/gates
      if (tid < 64) {
        int tk = 0; float g = 0.f;
        if (tid < nrow) { tk = ltok[base + tid]; g = lgate[base + tid]; }
        toks[tid] = tk; gates[tid] = g;
      }
      WAITLGKM0; SBAR;

      // stage X tile: fp32 global -> bf16 LDS (A-frag layout, 32-slot XOR swizzle)
      {
        int tm = tid >> 3, seg = tid & 7;
        bool valid = tm < nrow;
        const float* xp = x + (size_t)(valid ? toks[tm] : toks[0]) * DIM + seg * 64;
#pragma unroll
        for (int s2 = 0; s2 < 8; ++s2) {
          bf16x8 v;
          if (valid) {
            float4 f0 = *(const float4*)(xp + s2 * 8);
            float4 f1 = *(const float4*)(xp + s2 * 8 + 4);
            v[0] = (__bf16)f0.x; v[1] = (__bf16)f0.y; v[2] = (__bf16)f0.z; v[3] = (__bf16)f0.w;
            v[4] = (__bf16)f1.x; v[5] = (__bf16)f1.y; v[6] = (__bf16)f1.z; v[7] = (__bf16)f1.w;
          } else {
#pragma unroll
            for (int j = 0; j < 8; ++j) v[j] = (__bf16)0.f;
          }
          int ko = seg * 8 + s2;
          *(bf16x8*)&Xs[((size_t)tm * 64 + (ko ^ (tm & 31))) * 8] = v;
        }
      }
      WAITLGKM0; SBAR;                     // Xs ready (stages 0,1 landed via later vmcnt)

      f32x16 acc200, acc201, acc210, acc211;
#pragma unroll
      for (int r = 0; r < 16; ++r) { acc200[r] = 0.f; acc201[r] = 0.f; acc210[r] = 0.f; acc211[r] = 0.f; }

      int cs = 0, is_ = 2;

      for (int hc = 0; hc < 8; ++hc) {
        float bias = b1[e * HID + (hc * 8 + w) * 32 + lm];
        f32x16 acc10, acc11;
#pragma unroll
        for (int r = 0; r < 16; ++r) { acc10[r] = 0.f; acc11[r] = 0.f; }

        // ---- GEMM1: 16 sub-stages (K = 512) ----
#pragma unroll
        for (int ss = 0; ss < 16; ++ss) {
          issueStage(hc * 32 + ss + 2, is_); ADV3(is_);
          WAITVM(4); SCHEDB;
          const __bf16* rb = ringW + cs * 1024; ADV3(cs);
          __builtin_amdgcn_s_setprio(1);
#pragma unroll
          for (int kk = 0; kk < 2; ++kk) {
            int koX = (ss * 2 + kk) * 2 + hi;
            bf16x8 a0 = *(const bf16x8*)&Xs[((size_t)lm * 64 + (koX ^ lm)) * 8];
            bf16x8 a1 = *(const bf16x8*)&Xs[((size_t)(32 + lm) * 64 + (koX ^ lm)) * 8];
            bf16x8 b  = *(const bf16x8*)&rb[kk * 512 + hi * 256 + lm * 8];
            acc10 = mfma32(a0, b, acc10);
            acc11 = mfma32(a1, b, acc11);
          }
          __builtin_amdgcn_s_setprio(0);
        }

        // ---- bias + relu -> Hs (A-frag layout for GEMM2) ----
#pragma unroll
        for (int m = 0; m < 2; ++m)
#pragma unroll
          for (int r = 0; r < 16; ++r) {
            int tok = (r & 3) + 8 * (r >> 2) + 4 * hi + 32 * m;
            float v = fmaxf((m ? acc11[r] : acc10[r]) + bias, 0.f);
            int koW = (w * 4 + (lm >> 3)) ^ (tok & 31);
            Hs[((size_t)tok * 32 + koW) * 8 + (lm & 7)] = (__bf16)v;
          }
        WAITLGKM0; SBAR;                   // Hs ready for all waves

        // ---- GEMM2: 16 sub-stages (k-chunk of 256) ----
#pragma unroll
        for (int ss = 0; ss < 16; ++ss) {
          if (hc < 7 || ss < 14) { issueStage(hc * 32 + 16 + ss + 2, is_); ADV3(is_); }
          if (hc < 7 || ss < 14) { WAITVM(4); }
          else if (ss == 14)     { WAITVM(2); }
          else                   { WAITVM(0); }
          SCHEDB;
          const __bf16* rb = ringW + cs * 1024; ADV3(cs);
          int koH = ss * 2 + hi;
          bf16x8 h0  = *(const bf16x8*)&Hs[((size_t)lm * 32 + (koH ^ lm)) * 8];
          bf16x8 h1  = *(const bf16x8*)&Hs[((size_t)(32 + lm) * 32 + (koH ^ lm)) * 8];
          bf16x8 b0  = *(const bf16x8*)&rb[hi * 256 + lm * 8];
          bf16x8 b1v = *(const bf16x8*)&rb[512 + hi * 256 + lm * 8];
          __builtin_amdgcn_s_setprio(1);
          acc200 = mfma32(h0, b0, acc200);
          acc201 = mfma32(h1, b0, acc201);
          acc210 = mfma32(h0, b1v, acc210);
          acc211 = mfma32(h1, b1v, acc211);
          __builtin_amdgcn_s_setprio(0);
        }
        SBAR;                              // all waves done reading Hs before rewrite
      }

      // ---- epilogue: gate-weighted atomic accumulate, d-coalesced ----
      {
        int d0 = (2 * w) * 32 + lm;
        int d1 = (2 * w + 1) * 32 + lm;
#pragma unroll
        for (int m = 0; m < 2; ++m)
#pragma unroll
          for (int r = 0; r < 16; ++r) {
            int row = (r & 3) + 8 * (r >> 2) + 4 * hi + 32 * m;
            int tk = toks[row];
            float gg = gates[row];
            float* op = out + (size_t)tk * DIM;
            atomicAdd(op + d0, gg * ((m ? acc201[r] : acc200[r]) + b2r0));
            atomicAdd(op + d1, gg * ((m ? acc211[r] : acc210[r]) + b2r1));
          }
      }
    }
  }
}

extern "C" void kernel_launch(void* const* d_in, const int* in_sizes, int n_in,
                              void* d_out, int out_size, void* d_ws, size_t ws_size,
                              hipStream_t stream) {
  const float* x  = (const float*)d_in[0];
  const float* Wr = (const float*)d_in[1];
  const float* br = (const float*)d_in[2];
  const float* Wn = (const float*)d_in[3];
  const float* bn = (const float*)d_in[4];
  const float* W1 = (const float*)d_in[5];
  const float* b1 = (const float*)d_in[6];
  const float* W2 = (const float*)d_in[7];
  const float* b2 = (const float*)d_in[8];
  float* out = (float*)d_out;

  uint8_t* wsb = (uint8_t*)d_ws;
  int* fill     = (int*)(wsb + 64);
  int* ltok     = (int*)(wsb + 262272);   // 133120 B (33280 slots, 64-align pad)
  float* lgate  = (float*)(wsb + 395392); // 133120 B
  __bf16* W1p   = (__bf16*)(wsb + 528896);            // 16 MB
  __bf16* W2p   = (__bf16*)(wsb + 528896 + 16777216); // 16 MB
  // total ws usage: 528896 + 2*16777216 = 34,083,328 bytes (same as R3)

  void* args[] = {(void*)&x, (void*)&Wr, (void*)&br, (void*)&Wn, (void*)&bn,
                  (void*)&W1, (void*)&b1, (void*)&W2, (void*)&b2,
                  (void*)&W1p, (void*)&W2p,
                  (void*)&fill, (void*)&ltok, (void*)&lgate, (void*)&out};
  hipLaunchCooperativeKernel((const void*)fused_moe, dim3(256), dim3(512), args, 0, stream);
}